// Round 8
// baseline (496.924 us; speedup 1.0000x reference)
//
#include <hip/hip_runtime.h>

#define F_IN 128
#define RDIM 128
#define KTOT 384   // 2*F_IN + RDIM
#define ALPHA 0.2f

typedef short bf8 __attribute__((ext_vector_type(8)));   // 8 bf16 = 4 VGPRs
typedef float f4 __attribute__((ext_vector_type(4)));
typedef float fv4 __attribute__((ext_vector_type(4)));   // plain-vec float4 (nt-capable)
typedef float fv2 __attribute__((ext_vector_type(2)));
typedef int   iv4 __attribute__((ext_vector_type(4)));   // plain-vec int4   (nt-capable)

__device__ inline unsigned short f2bf(float f) {
  unsigned u = __float_as_uint(f);
  unsigned r = u + 0x7FFFu + ((u >> 16) & 1u);   // round-nearest-even
  return (unsigned short)(r >> 16);
}
__device__ inline float bf2f(unsigned short b) {
  return __uint_as_float((unsigned)b << 16);
}

// ---------- K_prep: fused {a -> bf16 | zero counts | w = a^T a_2} ----------
__global__ __launch_bounds__(256) void k_prep(const float* __restrict__ a,
                                              const float* __restrict__ a2,
                                              unsigned short* __restrict__ aB,
                                              int* __restrict__ counts,
                                              float* __restrict__ w,
                                              int N, int zb) {
  int b = blockIdx.x, t = threadIdx.x;
  if (b < 192) {
    int i = b * 256 + t;                     // < 49152 always
    aB[i] = f2bf(a[i]);
  } else if (b < 192 + zb) {
    int i = (b - 192) * 256 + t;
    if (i < N) counts[i] = 0;
  } else {
    int j = (b - 192 - zb) * 256 + t;
    if (j < KTOT) {
      float acc = 0.f;
      for (int f = 0; f < 128; ++f) acc += a2[f] * a[(size_t)f * KTOT + j];
      w[j] = acc;
    }
  }
}

// ---------- K1: s1/s2 dot products + input -> bf16 ----------
__global__ __launch_bounds__(256) void k_svec(const float* __restrict__ input,
                                              const float* __restrict__ w1,
                                              const float* __restrict__ w2,
                                              float* __restrict__ s1,
                                              float* __restrict__ s2,
                                              unsigned short* __restrict__ inputB,
                                              int N) {
  int lane = threadIdx.x & 63;
  int n = blockIdx.x * 4 + (threadIdx.x >> 6);
  if (n >= N) return;
  float2 x  = *(const float2*)(input + (size_t)n * F_IN + 2 * lane);
  float2 wa = *(const float2*)(w1 + 2 * lane);
  float2 wb = *(const float2*)(w2 + 2 * lane);
  ushort2 ib; ib.x = f2bf(x.x); ib.y = f2bf(x.y);
  *(ushort2*)(inputB + (size_t)n * F_IN + 2 * lane) = ib;
  float p1 = x.x * wa.x + x.y * wa.y;
  float p2 = x.x * wb.x + x.y * wb.y;
  #pragma unroll
  for (int m = 1; m < 64; m <<= 1) {
    p1 += __shfl_xor(p1, m, 64);
    p2 += __shfl_xor(p2, m, 64);
  }
  if (lane == 0) { s1[n] = p1; s2[n] = p2; }
}

// ---------- CSR build ----------
__global__ __launch_bounds__(256) void k_hist(const int* __restrict__ edge_src,
                                              int* __restrict__ counts, int E) {
  int e = blockIdx.x * 256 + threadIdx.x;
  if (e < E) atomicAdd(&counts[edge_src[e]], 1);
}

__global__ __launch_bounds__(1024) void k_scan(const int* __restrict__ counts,
                                               int* __restrict__ row_ptr,
                                               int* __restrict__ cursor, int N) {
  __shared__ int part[1024];
  int t = threadIdx.x;
  int per = (N + 1023) / 1024;
  int b = t * per;
  int e = b + per; if (e > N) e = N;
  int s = 0;
  for (int i = b; i < e; ++i) s += counts[i];
  part[t] = s;
  __syncthreads();
  for (int off = 1; off < 1024; off <<= 1) {
    int v = (t >= off) ? part[t - off] : 0;
    __syncthreads();
    part[t] += v;
    __syncthreads();
  }
  int run = part[t] - s;
  for (int i = b; i < e; ++i) { row_ptr[i] = run; cursor[i] = run; run += counts[i]; }
  if (t == 1023) row_ptr[N] = part[1023];
}

// ---------- K_logit: ee[e] = exp(-leakyrelu(s1[src]+s2[dst]+emb[e]·w3)) ----------
// 16 edges per wave, 4 lanes per edge; emb read is a contiguous 8KB/wave stream.
// Each block (4 waves) covers 64 edges -> grid = ceil(E/64).
__global__ __launch_bounds__(256) void k_logit(const float* __restrict__ emb,
                                               const float* __restrict__ w3,
                                               const int* __restrict__ edge_src,
                                               const int* __restrict__ edge_dst,
                                               const float* __restrict__ s1,
                                               const float* __restrict__ s2,
                                               float* __restrict__ ee, int E) {
  int wid = (blockIdx.x * 256 + threadIdx.x) >> 6;
  int lane = threadIdx.x & 63;
  int eg = lane >> 2, sub = lane & 3;
  int e = wid * 16 + eg;
  bool val = e < E;
  float q = 0.f;
  const float* er = emb + (size_t)e * RDIM + sub * 4;
  const float* wr = w3 + sub * 4;
  #pragma unroll
  for (int j = 0; j < 8; ++j) {
    fv4 x = val ? __builtin_nontemporal_load((const fv4*)(er + j * 16)) : (fv4)(0.f);
    fv4 wv = *(const fv4*)(wr + j * 16);
    q += x.x * wv.x + x.y * wv.y + x.z * wv.z + x.w * wv.w;
  }
  q += __shfl_xor(q, 1, 64);
  q += __shfl_xor(q, 2, 64);
  if (val && sub == 0) {
    float s = s1[edge_src[e]] + s2[edge_dst[e]] + q;
    float lr = s > 0.f ? s : ALPHA * s;
    __builtin_nontemporal_store(__expf(-lr), &ee[e]);
  }
}

// ---------- K_scatter: pack {e, dst, ee} into CSR slots ----------
__global__ __launch_bounds__(256) void k_scatter(const int* __restrict__ edge_src,
                                                 const int* __restrict__ edge_dst,
                                                 const float* __restrict__ ee,
                                                 int* __restrict__ cursor,
                                                 iv4* __restrict__ csr_pack, int E) {
  int e = blockIdx.x * 256 + threadIdx.x;
  if (e >= E) return;
  int src = edge_src[e];
  int dst = edge_dst[e];
  float v = ee[e];
  int pos = atomicAdd(&cursor[src], 1);
  iv4 pk; pk.x = e; pk.y = dst; pk.z = __float_as_int(v); pk.w = 0;
  __builtin_nontemporal_store(pk, &csr_pack[pos]);
}

// ---------- K_gather: per-node wave; no cross-lane ops in loop; depth-2 pipeline ----
// G[n] = [ (Σ ee*inputB[dst])/rs | (Σ ee*emb[e])/rs ]  -> bf16 (256 elems)
__global__ __launch_bounds__(256) void k_gather(const unsigned short* __restrict__ inputB,
                                                const float* __restrict__ emb,
                                                const int* __restrict__ row_ptr,
                                                const iv4* __restrict__ csr_pack,
                                                unsigned short* __restrict__ Gb,
                                                float* __restrict__ rs, int N) {
  int lane = threadIdx.x & 63;
  int n = blockIdx.x * 4 + (threadIdx.x >> 6);
  if (n >= N) return;
  int beg = row_ptr[n], end = row_ptr[n + 1];
  float gix = 0.f, giy = 0.f, gex = 0.f, gey = 0.f, rsum = 0.f;

  fv2 z2; z2.x = 0.f; z2.y = 0.f;
  fv2 x0 = z2, x1 = z2;
  ushort2 y0 = make_ushort2(0, 0), y1 = y0;
  float ee0 = 0.f, ee1 = 0.f;
  iv4 pc; pc.x = 0; pc.y = 0; pc.z = 0; pc.w = 0;

  if (beg < end) {
    iv4 p = __builtin_nontemporal_load(&csr_pack[beg]);
    ee0 = __int_as_float(p.z);
    x0 = __builtin_nontemporal_load((const fv2*)(emb + (size_t)p.x * RDIM + 2 * lane));
    y0 = *(const ushort2*)(inputB + (size_t)p.y * F_IN + 2 * lane);
  }
  if (beg + 1 < end) {
    iv4 p = __builtin_nontemporal_load(&csr_pack[beg + 1]);
    ee1 = __int_as_float(p.z);
    x1 = __builtin_nontemporal_load((const fv2*)(emb + (size_t)p.x * RDIM + 2 * lane));
    y1 = *(const ushort2*)(inputB + (size_t)p.y * F_IN + 2 * lane);
  }
  if (beg + 2 < end) pc = __builtin_nontemporal_load(&csr_pack[beg + 2]);

  for (int i = beg; i < end; ++i) {
    // prefetch data for edge i+2; payload for i+3
    fv2 xn = z2;
    ushort2 yn = make_ushort2(0, 0);
    float een = 0.f;
    if (i + 2 < end) {
      een = __int_as_float(pc.z);
      xn = __builtin_nontemporal_load((const fv2*)(emb + (size_t)pc.x * RDIM + 2 * lane));
      yn = *(const ushort2*)(inputB + (size_t)pc.y * F_IN + 2 * lane);
    }
    if (i + 3 < end) pc = __builtin_nontemporal_load(&csr_pack[i + 3]);
    // accumulate slot 0 (no cross-lane ops)
    rsum += ee0;
    gix += ee0 * bf2f(y0.x); giy += ee0 * bf2f(y0.y);
    gex += ee0 * x0.x;       gey += ee0 * x0.y;
    // rotate
    x0 = x1; y0 = y1; ee0 = ee1;
    x1 = xn; y1 = yn; ee1 = een;
  }

  float scale = rsum > 0.f ? 1.f / rsum : 0.f;
  unsigned short* Gn = Gb + (size_t)n * 256;
  ushort2 o;
  o.x = f2bf(gix * scale); o.y = f2bf(giy * scale);
  *(ushort2*)(Gn + 2 * lane) = o;
  o.x = f2bf(gex * scale); o.y = f2bf(gey * scale);
  *(ushort2*)(Gn + 128 + 2 * lane) = o;
  if (lane == 0) rs[n] = rsum;
}

// ---------- K4: MFMA bf16 GEMM: out = elu([inputB | Gb] @ aB^T), rs==0 rows -> 0 ----
__global__ __launch_bounds__(256) void k_out(const unsigned short* __restrict__ inputB,
                                             const unsigned short* __restrict__ Gb,
                                             const unsigned short* __restrict__ aB,
                                             const float* __restrict__ rs,
                                             float* __restrict__ out, int N) {
  int t = threadIdx.x;
  int w = t >> 6, lane = t & 63;
  int lg = lane >> 4, lr = lane & 15;
  int rowbase = blockIdx.x * 128 + w * 32;
  int koff = lg * 8;

  f4 acc[2][8];
  #pragma unroll
  for (int r = 0; r < 2; ++r)
    #pragma unroll
    for (int c = 0; c < 8; ++c) acc[r][c] = (f4)(0.f);

  #pragma unroll
  for (int ks = 0; ks < 12; ++ks) {
    const int k0 = ks * 32;
    bf8 Af[2], Bf[8];
    #pragma unroll
    for (int r = 0; r < 2; ++r) {
      int row = rowbase + r * 16 + lr;
      if (k0 < 128)
        Af[r] = *(const bf8*)(inputB + (size_t)row * 128 + k0 + koff);
      else
        Af[r] = *(const bf8*)(Gb + (size_t)row * 256 + (k0 - 128) + koff);
    }
    #pragma unroll
    for (int c = 0; c < 8; ++c)
      Bf[c] = *(const bf8*)(aB + (size_t)(c * 16 + lr) * KTOT + k0 + koff);
    #pragma unroll
    for (int r = 0; r < 2; ++r)
      #pragma unroll
      for (int c = 0; c < 8; ++c)
        acc[r][c] = __builtin_amdgcn_mfma_f32_16x16x32_bf16(Af[r], Bf[c], acc[r][c], 0, 0, 0);
  }

  #pragma unroll
  for (int r = 0; r < 2; ++r) {
    #pragma unroll
    for (int j = 0; j < 4; ++j) {
      int row = rowbase + r * 16 + lg * 4 + j;
      if (row >= N) continue;
      float rsv = rs[row];
      #pragma unroll
      for (int c = 0; c < 8; ++c) {
        float v = acc[r][c][j];
        float hh = v > 0.f ? v : (__expf(v) - 1.f);
        out[(size_t)row * 128 + c * 16 + lr] = (rsv == 0.f) ? 0.f : hh;
      }
    }
  }
}

extern "C" void kernel_launch(void* const* d_in, const int* in_sizes, int n_in,
                              void* d_out, int out_size, void* d_ws, size_t ws_size,
                              hipStream_t stream) {
  const float* input      = (const float*)d_in[0];
  const int*   edge       = (const int*)d_in[1];   // int32 [2,E] row-major
  const float* edge_embed = (const float*)d_in[2];
  const float* a          = (const float*)d_in[3];
  const float* a_2        = (const float*)d_in[4];
  float* out = (float*)d_out;
  int N = in_sizes[0] / F_IN;
  int E = in_sizes[1] / 2;
  const int* edge_src = edge;
  const int* edge_dst = edge + E;

  char* p = (char*)d_ws;
  auto take = [&](size_t bytes) { char* q = p; p += (bytes + 255) & ~(size_t)255; return q; };
  float* w        = (float*)take(KTOT * 4);        // w1|w2|w3 contiguous
  float* s1       = (float*)take((size_t)N * 4);
  float* s2       = (float*)take((size_t)N * 4);
  float* rs       = (float*)take((size_t)N * 4);
  int*   counts   = (int*)take((size_t)N * 4);
  int*   cursor   = (int*)take((size_t)N * 4);
  int*   row_ptr  = (int*)take((size_t)(N + 1) * 4);
  unsigned short* aB     = (unsigned short*)take((size_t)128 * KTOT * 2);
  unsigned short* inputB = (unsigned short*)take((size_t)N * 128 * 2);
  float* ee       = (float*)take((size_t)E * 4);
  iv4*  csr_pack  = (iv4*)take((size_t)E * 16);
  unsigned short* Gb     = (unsigned short*)take((size_t)N * 256 * 2);
  (void)take(64 * 1024);   // tail pad: k_out overreads <=48 rows past N

  int zb = (N + 255) / 256;
  k_prep<<<192 + zb + 2, 256, 0, stream>>>(a, a_2, aB, counts, w, N, zb);
  k_svec<<<(N + 3) / 4, 256, 0, stream>>>(input, w, w + 128, s1, s2, inputB, N);
  k_hist<<<(E + 255) / 256, 256, 0, stream>>>(edge_src, counts, E);
  k_scan<<<1, 1024, 0, stream>>>(counts, row_ptr, cursor, N);
  k_logit<<<(E + 63) / 64, 256, 0, stream>>>(edge_embed, w + 256, edge_src, edge_dst,
                                             s1, s2, ee, E);
  k_scatter<<<(E + 255) / 256, 256, 0, stream>>>(edge_src, edge_dst, ee, cursor,
                                                 csr_pack, E);
  k_gather<<<(N + 3) / 4, 256, 0, stream>>>(inputB, edge_embed, row_ptr, csr_pack,
                                            Gb, rs, N);
  k_out<<<(N + 127) / 128, 256, 0, stream>>>(inputB, Gb, aB, rs, out, N);
}

// Round 9
// 277.570 us; speedup vs baseline: 1.7903x; 1.7903x over previous
//
#include <hip/hip_runtime.h>

#define F_IN 128
#define RDIM 128
#define KTOT 384   // 2*F_IN + RDIM
#define ALPHA 0.2f

typedef short bf8 __attribute__((ext_vector_type(8)));   // 8 bf16 = 4 VGPRs
typedef float f4 __attribute__((ext_vector_type(4)));
typedef float fv4 __attribute__((ext_vector_type(4)));   // plain-vec float4 (nt-capable)
typedef int   iv4 __attribute__((ext_vector_type(4)));   // plain-vec int4   (nt-capable)

__device__ inline unsigned short f2bf(float f) {
  unsigned u = __float_as_uint(f);
  unsigned r = u + 0x7FFFu + ((u >> 16) & 1u);   // round-nearest-even
  return (unsigned short)(r >> 16);
}

// ---------- K_prep: fused {a -> bf16 | zero counts | w = a^T a_2} ----------
__global__ __launch_bounds__(256) void k_prep(const float* __restrict__ a,
                                              const float* __restrict__ a2,
                                              unsigned short* __restrict__ aB,
                                              int* __restrict__ counts,
                                              float* __restrict__ w,
                                              int N, int zb) {
  int b = blockIdx.x, t = threadIdx.x;
  if (b < 192) {
    int i = b * 256 + t;                     // < 49152 always
    aB[i] = f2bf(a[i]);
  } else if (b < 192 + zb) {
    int i = (b - 192) * 256 + t;
    if (i < N) counts[i] = 0;
  } else {
    int j = (b - 192 - zb) * 256 + t;
    if (j < KTOT) {
      float acc = 0.f;
      for (int f = 0; f < 128; ++f) acc += a2[f] * a[(size_t)f * KTOT + j];
      w[j] = acc;
    }
  }
}

// ---------- K_sh: fused { svec (s1,s2,inputB) | hist (counts atomics) } ----------
__global__ __launch_bounds__(256) void k_sh(const float* __restrict__ input,
                                            const float* __restrict__ w1,
                                            const float* __restrict__ w2,
                                            float* __restrict__ s1,
                                            float* __restrict__ s2,
                                            unsigned short* __restrict__ inputB,
                                            const int* __restrict__ edge_src,
                                            int* __restrict__ counts,
                                            int N, int E, int SV) {
  int b = blockIdx.x, t = threadIdx.x;
  if (b < SV) {
    int lane = t & 63;
    int n = b * 4 + (t >> 6);
    if (n >= N) return;
    float2 x  = *(const float2*)(input + (size_t)n * F_IN + 2 * lane);
    float2 wa = *(const float2*)(w1 + 2 * lane);
    float2 wb = *(const float2*)(w2 + 2 * lane);
    ushort2 ib; ib.x = f2bf(x.x); ib.y = f2bf(x.y);
    *(ushort2*)(inputB + (size_t)n * F_IN + 2 * lane) = ib;
    float p1 = x.x * wa.x + x.y * wa.y;
    float p2 = x.x * wb.x + x.y * wb.y;
    #pragma unroll
    for (int m = 1; m < 64; m <<= 1) {
      p1 += __shfl_xor(p1, m, 64);
      p2 += __shfl_xor(p2, m, 64);
    }
    if (lane == 0) { s1[n] = p1; s2[n] = p2; }
  } else {
    int i = (b - SV) * 1024 + 4 * t;
    if (i + 3 < E) {
      iv4 s = *(const iv4*)(edge_src + i);
      atomicAdd(&counts[s.x], 1);
      atomicAdd(&counts[s.y], 1);
      atomicAdd(&counts[s.z], 1);
      atomicAdd(&counts[s.w], 1);
    } else {
      for (int j = i; j < E; ++j) atomicAdd(&counts[edge_src[j]], 1);
    }
  }
}

// ---------- multi-block exclusive scan: A = local scan + block sums ----------
__global__ __launch_bounds__(256) void k_scanA(const int* __restrict__ counts,
                                               int* __restrict__ row_ptr,
                                               int* __restrict__ bsums, int N) {
  __shared__ int sh[256];
  int b = blockIdx.x, t = threadIdx.x;
  int i0 = b * 1024 + 4 * t;
  iv4 c; c.x = 0; c.y = 0; c.z = 0; c.w = 0;
  if (i0 + 3 < N) c = *(const iv4*)(counts + i0);
  else {
    if (i0 + 0 < N) c.x = counts[i0 + 0];
    if (i0 + 1 < N) c.y = counts[i0 + 1];
    if (i0 + 2 < N) c.z = counts[i0 + 2];
    if (i0 + 3 < N) c.w = counts[i0 + 3];
  }
  int s = c.x + c.y + c.z + c.w;
  sh[t] = s;
  __syncthreads();
  #pragma unroll
  for (int off = 1; off < 256; off <<= 1) {
    int v = (t >= off) ? sh[t - off] : 0;
    __syncthreads();
    sh[t] += v;
    __syncthreads();
  }
  int excl = sh[t] - s;
  iv4 o;
  o.x = excl;
  o.y = excl + c.x;
  o.z = excl + c.x + c.y;
  o.w = excl + c.x + c.y + c.z;
  if (i0 + 3 < N) *(iv4*)(row_ptr + i0) = o;
  else {
    if (i0 + 0 < N) row_ptr[i0 + 0] = o.x;
    if (i0 + 1 < N) row_ptr[i0 + 1] = o.y;
    if (i0 + 2 < N) row_ptr[i0 + 2] = o.z;
    if (i0 + 3 < N) row_ptr[i0 + 3] = o.w;
  }
  if (t == 255) bsums[b] = sh[255];
}

// ---------- scan B: add block offsets (in place) + cursor init + row_ptr[N] ----
__global__ __launch_bounds__(256) void k_scanB(int* __restrict__ row_ptr,
                                               int* __restrict__ cursor,
                                               const int* __restrict__ bsums,
                                               int N, int NB) {
  int b = blockIdx.x, t = threadIdx.x, lane = t & 63;
  int off = 0, total = 0;
  for (int j = lane; j < NB; j += 64) {
    int v = bsums[j];
    if (j < b) off += v;
    total += v;
  }
  #pragma unroll
  for (int m = 1; m < 64; m <<= 1) {
    off += __shfl_xor(off, m, 64);
    total += __shfl_xor(total, m, 64);
  }
  int i0 = b * 1024 + 4 * t;
  if (i0 + 3 < N) {
    iv4 v = *(const iv4*)(row_ptr + i0);
    v.x += off; v.y += off; v.z += off; v.w += off;
    *(iv4*)(row_ptr + i0) = v;
    *(iv4*)(cursor + i0) = v;
  } else {
    for (int j = i0; j < N && j < i0 + 4; ++j) {
      int v = row_ptr[j] + off;
      row_ptr[j] = v;
      cursor[j] = v;
    }
  }
  if (b == NB - 1 && t == 0) row_ptr[N] = total;
}

// ---------- K_scatter: pack {e, dst, s2[dst]} into CSR slots ----------
__global__ __launch_bounds__(256) void k_scatter(const int* __restrict__ edge_src,
                                                 const int* __restrict__ edge_dst,
                                                 const float* __restrict__ s2,
                                                 int* __restrict__ cursor,
                                                 iv4* __restrict__ csr_pack, int E) {
  int e = blockIdx.x * 256 + threadIdx.x;
  if (e >= E) return;
  int src = edge_src[e];
  int dst = edge_dst[e];
  float sv = s2[dst];
  int pos = atomicAdd(&cursor[src], 1);
  iv4 pk; pk.x = e; pk.y = dst; pk.z = __float_as_int(sv); pk.w = 0;
  __builtin_nontemporal_store(pk, &csr_pack[pos]);
}

// ---------- K_edge: per-node wave; 2 edges/iter; depth-2 pipeline; nt; bf16 G ----
__global__ __launch_bounds__(256) void k_edge(const float* __restrict__ input,
                                              const float* __restrict__ emb,
                                              const float* __restrict__ w3,
                                              const float* __restrict__ s1,
                                              const int* __restrict__ row_ptr,
                                              const iv4* __restrict__ csr_pack,
                                              unsigned short* __restrict__ Gb,
                                              float* __restrict__ rs, int N) {
  int lane = threadIdx.x & 63;
  int h = lane >> 5;     // which edge of the pair
  int c = lane & 31;     // feature sublane: features 4c..4c+3
  int n = blockIdx.x * 4 + (threadIdx.x >> 6);
  if (n >= N) return;
  int beg = row_ptr[n], end = row_ptr[n + 1];
  fv4 w3v = *(const fv4*)(w3 + 4 * c);
  float s1n = s1[n];
  fv4 gi = (fv4)(0.f), ge = (fv4)(0.f);
  float rsum = 0.f;

  fv4 z4 = (fv4)(0.f);
  fv4 x0 = z4, y0 = z4, x1 = z4, y1 = z4;
  float sv0 = 0.f, sv1 = 0.f;
  bool va0 = false, va1 = false;
  iv4 pN; pN.x = 0; pN.y = 0; pN.z = 0; pN.w = 0;

  int i0 = beg + h;
  if (i0 < end) {
    iv4 p = __builtin_nontemporal_load(&csr_pack[i0]);
    sv0 = __int_as_float(p.z);
    x0 = __builtin_nontemporal_load((const fv4*)(emb + (size_t)p.x * RDIM + 4 * c));
    y0 = *(const fv4*)(input + (size_t)p.y * F_IN + 4 * c);
    va0 = true;
  }
  if (i0 + 2 < end) {
    iv4 p = __builtin_nontemporal_load(&csr_pack[i0 + 2]);
    sv1 = __int_as_float(p.z);
    x1 = __builtin_nontemporal_load((const fv4*)(emb + (size_t)p.x * RDIM + 4 * c));
    y1 = *(const fv4*)(input + (size_t)p.y * F_IN + 4 * c);
    va1 = true;
  }
  if (i0 + 4 < end) pN = __builtin_nontemporal_load(&csr_pack[i0 + 4]);

  for (int i = beg; i < end; i += 2) {
    fv4 xn = z4, yn = z4;
    float svn = __int_as_float(pN.z);
    bool vn = (i + 4 + h) < end;
    if (vn) {
      xn = __builtin_nontemporal_load((const fv4*)(emb + (size_t)pN.x * RDIM + 4 * c));
      yn = *(const fv4*)(input + (size_t)pN.y * F_IN + 4 * c);
    }
    if (i + 6 + h < end) pN = __builtin_nontemporal_load(&csr_pack[i + 6 + h]);
    // compute on slot 0
    float q = x0.x * w3v.x + x0.y * w3v.y + x0.z * w3v.z + x0.w * w3v.w;
    #pragma unroll
    for (int m = 1; m < 32; m <<= 1) q += __shfl_xor(q, m, 64);  // within-half reduce
    float s = s1n + sv0 + q;
    float lr = s > 0.f ? s : ALPHA * s;
    float ee = va0 ? __expf(-lr) : 0.f;
    rsum += ee;
    gi.x += ee * y0.x; gi.y += ee * y0.y; gi.z += ee * y0.z; gi.w += ee * y0.w;
    ge.x += ee * x0.x; ge.y += ee * x0.y; ge.z += ee * x0.z; ge.w += ee * x0.w;
    x0 = x1; y0 = y1; sv0 = sv1; va0 = va1;
    x1 = xn; y1 = yn; sv1 = svn; va1 = vn;
  }

  rsum += __shfl_xor(rsum, 32, 64);
  gi.x += __shfl_xor(gi.x, 32, 64); gi.y += __shfl_xor(gi.y, 32, 64);
  gi.z += __shfl_xor(gi.z, 32, 64); gi.w += __shfl_xor(gi.w, 32, 64);
  ge.x += __shfl_xor(ge.x, 32, 64); ge.y += __shfl_xor(ge.y, 32, 64);
  ge.z += __shfl_xor(ge.z, 32, 64); ge.w += __shfl_xor(ge.w, 32, 64);

  float scale = rsum > 0.f ? 1.f / rsum : 0.f;
  if (h == 0) {
    unsigned short* Gn = Gb + (size_t)n * 256;
    ushort4 o;
    o.x = f2bf(gi.x * scale); o.y = f2bf(gi.y * scale);
    o.z = f2bf(gi.z * scale); o.w = f2bf(gi.w * scale);
    *(ushort4*)(Gn + 4 * c) = o;
    o.x = f2bf(ge.x * scale); o.y = f2bf(ge.y * scale);
    o.z = f2bf(ge.z * scale); o.w = f2bf(ge.w * scale);
    *(ushort4*)(Gn + 128 + 4 * c) = o;
  }
  if (lane == 0) rs[n] = rsum;
}

// ---------- K_out: MFMA bf16 GEMM: out = elu([inputB | Gb] @ aB^T), rs==0 -> 0 ----
__global__ __launch_bounds__(256) void k_out(const unsigned short* __restrict__ inputB,
                                             const unsigned short* __restrict__ Gb,
                                             const unsigned short* __restrict__ aB,
                                             const float* __restrict__ rs,
                                             float* __restrict__ out, int N) {
  int t = threadIdx.x;
  int w = t >> 6, lane = t & 63;
  int lg = lane >> 4, lr = lane & 15;
  int rowbase = blockIdx.x * 128 + w * 32;
  int koff = lg * 8;

  f4 acc[2][8];
  #pragma unroll
  for (int r = 0; r < 2; ++r)
    #pragma unroll
    for (int c = 0; c < 8; ++c) acc[r][c] = (f4)(0.f);

  #pragma unroll
  for (int ks = 0; ks < 12; ++ks) {
    const int k0 = ks * 32;
    bf8 Af[2], Bf[8];
    #pragma unroll
    for (int r = 0; r < 2; ++r) {
      int row = rowbase + r * 16 + lr;
      if (k0 < 128)
        Af[r] = *(const bf8*)(inputB + (size_t)row * 128 + k0 + koff);
      else
        Af[r] = *(const bf8*)(Gb + (size_t)row * 256 + (k0 - 128) + koff);
    }
    #pragma unroll
    for (int c = 0; c < 8; ++c)
      Bf[c] = *(const bf8*)(aB + (size_t)(c * 16 + lr) * KTOT + k0 + koff);
    #pragma unroll
    for (int r = 0; r < 2; ++r)
      #pragma unroll
      for (int c = 0; c < 8; ++c)
        acc[r][c] = __builtin_amdgcn_mfma_f32_16x16x32_bf16(Af[r], Bf[c], acc[r][c], 0, 0, 0);
  }

  #pragma unroll
  for (int r = 0; r < 2; ++r) {
    #pragma unroll
    for (int j = 0; j < 4; ++j) {
      int row = rowbase + r * 16 + lg * 4 + j;
      if (row >= N) continue;
      float rsv = rs[row];
      #pragma unroll
      for (int c = 0; c < 8; ++c) {
        float v = acc[r][c][j];
        float hh = v > 0.f ? v : (__expf(v) - 1.f);
        out[(size_t)row * 128 + c * 16 + lr] = (rsv == 0.f) ? 0.f : hh;
      }
    }
  }
}

extern "C" void kernel_launch(void* const* d_in, const int* in_sizes, int n_in,
                              void* d_out, int out_size, void* d_ws, size_t ws_size,
                              hipStream_t stream) {
  const float* input      = (const float*)d_in[0];
  const int*   edge       = (const int*)d_in[1];   // int32 [2,E] row-major
  const float* edge_embed = (const float*)d_in[2];
  const float* a          = (const float*)d_in[3];
  const float* a_2        = (const float*)d_in[4];
  float* out = (float*)d_out;
  int N = in_sizes[0] / F_IN;
  int E = in_sizes[1] / 2;
  const int* edge_src = edge;
  const int* edge_dst = edge + E;

  char* p = (char*)d_ws;
  auto take = [&](size_t bytes) { char* q = p; p += (bytes + 255) & ~(size_t)255; return q; };
  float* w        = (float*)take(KTOT * 4);        // w1|w2|w3 contiguous
  float* s1       = (float*)take((size_t)N * 4);
  float* s2       = (float*)take((size_t)N * 4);
  float* rs       = (float*)take((size_t)N * 4);
  int*   counts   = (int*)take((size_t)N * 4);
  int*   cursor   = (int*)take((size_t)N * 4);
  int*   row_ptr  = (int*)take((size_t)(N + 1) * 4);
  int*   bsums    = (int*)take(256 * 4);
  unsigned short* aB     = (unsigned short*)take((size_t)128 * KTOT * 2);
  unsigned short* inputB = (unsigned short*)take((size_t)N * 128 * 2);
  iv4*  csr_pack  = (iv4*)take((size_t)E * 16);
  unsigned short* Gb     = (unsigned short*)take((size_t)N * 256 * 2);
  (void)take(64 * 1024);   // tail pad: k_out overreads <=48 rows past N

  int zb = (N + 255) / 256;
  int SV = (N + 3) / 4;
  int HB = (E + 1023) / 1024;
  int NB = (N + 1023) / 1024;

  k_prep<<<192 + zb + 2, 256, 0, stream>>>(a, a_2, aB, counts, w, N, zb);
  k_sh<<<SV + HB, 256, 0, stream>>>(input, w, w + 128, s1, s2, inputB,
                                    edge_src, counts, N, E, SV);
  k_scanA<<<NB, 256, 0, stream>>>(counts, row_ptr, bsums, N);
  k_scanB<<<NB, 256, 0, stream>>>(row_ptr, cursor, bsums, N, NB);
  k_scatter<<<(E + 255) / 256, 256, 0, stream>>>(edge_src, edge_dst, s2, cursor,
                                                 csr_pack, E);
  k_edge<<<(N + 3) / 4, 256, 0, stream>>>(input, edge_embed, w + 256, s1,
                                          row_ptr, csr_pack, Gb, rs, N);
  k_out<<<(N + 127) / 128, 256, 0, stream>>>(inputB, Gb, aB, rs, out, N);
}

// Round 10
// 271.383 us; speedup vs baseline: 1.8311x; 1.0228x over previous
//
#include <hip/hip_runtime.h>

#define F_IN 128
#define RDIM 128
#define KTOT 384   // 2*F_IN + RDIM
#define ALPHA 0.2f

typedef short bf8 __attribute__((ext_vector_type(8)));   // 8 bf16 = 4 VGPRs
typedef float f4 __attribute__((ext_vector_type(4)));
typedef float fv4 __attribute__((ext_vector_type(4)));   // plain-vec float4 (nt-capable)
typedef int   iv4 __attribute__((ext_vector_type(4)));   // plain-vec int4   (nt-capable)

__device__ inline unsigned short f2bf(float f) {
  unsigned u = __float_as_uint(f);
  unsigned r = u + 0x7FFFu + ((u >> 16) & 1u);   // round-nearest-even
  return (unsigned short)(r >> 16);
}
__device__ inline float bf2f(unsigned short b) {
  return __uint_as_float((unsigned)b << 16);
}

// ---------- K_prep: fused {a -> bf16 | zero counts | w = a^T a_2} ----------
__global__ __launch_bounds__(256) void k_prep(const float* __restrict__ a,
                                              const float* __restrict__ a2,
                                              unsigned short* __restrict__ aB,
                                              int* __restrict__ counts,
                                              float* __restrict__ w,
                                              int N, int zb) {
  int b = blockIdx.x, t = threadIdx.x;
  if (b < 192) {
    int i = b * 256 + t;                     // < 49152 always
    aB[i] = f2bf(a[i]);
  } else if (b < 192 + zb) {
    int i = (b - 192) * 256 + t;
    if (i < N) counts[i] = 0;
  } else {
    int j = (b - 192 - zb) * 256 + t;
    if (j < KTOT) {
      float acc = 0.f;
      for (int f = 0; f < 128; ++f) acc += a2[f] * a[(size_t)f * KTOT + j];
      w[j] = acc;
    }
  }
}

// ---------- K_sh: fused { svec (s1,s2,inputB) | hist (counts atomics) } ----------
__global__ __launch_bounds__(256) void k_sh(const float* __restrict__ input,
                                            const float* __restrict__ w1,
                                            const float* __restrict__ w2,
                                            float* __restrict__ s1,
                                            float* __restrict__ s2,
                                            unsigned short* __restrict__ inputB,
                                            const int* __restrict__ edge_src,
                                            int* __restrict__ counts,
                                            int N, int E, int SV) {
  int b = blockIdx.x, t = threadIdx.x;
  if (b < SV) {
    int lane = t & 63;
    int n = b * 4 + (t >> 6);
    if (n >= N) return;
    float2 x  = *(const float2*)(input + (size_t)n * F_IN + 2 * lane);
    float2 wa = *(const float2*)(w1 + 2 * lane);
    float2 wb = *(const float2*)(w2 + 2 * lane);
    ushort2 ib; ib.x = f2bf(x.x); ib.y = f2bf(x.y);
    *(ushort2*)(inputB + (size_t)n * F_IN + 2 * lane) = ib;
    float p1 = x.x * wa.x + x.y * wa.y;
    float p2 = x.x * wb.x + x.y * wb.y;
    #pragma unroll
    for (int m = 1; m < 64; m <<= 1) {
      p1 += __shfl_xor(p1, m, 64);
      p2 += __shfl_xor(p2, m, 64);
    }
    if (lane == 0) { s1[n] = p1; s2[n] = p2; }
  } else {
    int i = (b - SV) * 1024 + 4 * t;
    if (i + 3 < E) {
      iv4 s = *(const iv4*)(edge_src + i);
      atomicAdd(&counts[s.x], 1);
      atomicAdd(&counts[s.y], 1);
      atomicAdd(&counts[s.z], 1);
      atomicAdd(&counts[s.w], 1);
    } else {
      for (int j = i; j < E; ++j) atomicAdd(&counts[edge_src[j]], 1);
    }
  }
}

// ---------- multi-block exclusive scan: A = local scan + block sums ----------
__global__ __launch_bounds__(256) void k_scanA(const int* __restrict__ counts,
                                               int* __restrict__ row_ptr,
                                               int* __restrict__ bsums, int N) {
  __shared__ int sh[256];
  int b = blockIdx.x, t = threadIdx.x;
  int i0 = b * 1024 + 4 * t;
  iv4 c; c.x = 0; c.y = 0; c.z = 0; c.w = 0;
  if (i0 + 3 < N) c = *(const iv4*)(counts + i0);
  else {
    if (i0 + 0 < N) c.x = counts[i0 + 0];
    if (i0 + 1 < N) c.y = counts[i0 + 1];
    if (i0 + 2 < N) c.z = counts[i0 + 2];
    if (i0 + 3 < N) c.w = counts[i0 + 3];
  }
  int s = c.x + c.y + c.z + c.w;
  sh[t] = s;
  __syncthreads();
  #pragma unroll
  for (int off = 1; off < 256; off <<= 1) {
    int v = (t >= off) ? sh[t - off] : 0;
    __syncthreads();
    sh[t] += v;
    __syncthreads();
  }
  int excl = sh[t] - s;
  iv4 o;
  o.x = excl;
  o.y = excl + c.x;
  o.z = excl + c.x + c.y;
  o.w = excl + c.x + c.y + c.z;
  if (i0 + 3 < N) *(iv4*)(row_ptr + i0) = o;
  else {
    if (i0 + 0 < N) row_ptr[i0 + 0] = o.x;
    if (i0 + 1 < N) row_ptr[i0 + 1] = o.y;
    if (i0 + 2 < N) row_ptr[i0 + 2] = o.z;
    if (i0 + 3 < N) row_ptr[i0 + 3] = o.w;
  }
  if (t == 255) bsums[b] = sh[255];
}

// ---------- scan B: add block offsets (in place) + cursor init + row_ptr[N] ----
__global__ __launch_bounds__(256) void k_scanB(int* __restrict__ row_ptr,
                                               int* __restrict__ cursor,
                                               const int* __restrict__ bsums,
                                               int N, int NB) {
  int b = blockIdx.x, t = threadIdx.x, lane = t & 63;
  int off = 0, total = 0;
  for (int j = lane; j < NB; j += 64) {
    int v = bsums[j];
    if (j < b) off += v;
    total += v;
  }
  #pragma unroll
  for (int m = 1; m < 64; m <<= 1) {
    off += __shfl_xor(off, m, 64);
    total += __shfl_xor(total, m, 64);
  }
  int i0 = b * 1024 + 4 * t;
  if (i0 + 3 < N) {
    iv4 v = *(const iv4*)(row_ptr + i0);
    v.x += off; v.y += off; v.z += off; v.w += off;
    *(iv4*)(row_ptr + i0) = v;
    *(iv4*)(cursor + i0) = v;
  } else {
    for (int j = i0; j < N && j < i0 + 4; ++j) {
      int v = row_ptr[j] + off;
      row_ptr[j] = v;
      cursor[j] = v;
    }
  }
  if (b == NB - 1 && t == 0) row_ptr[N] = total;
}

// ---------- K_scatter: pack {e, dst, s2[dst]} into CSR slots ----------
__global__ __launch_bounds__(256) void k_scatter(const int* __restrict__ edge_src,
                                                 const int* __restrict__ edge_dst,
                                                 const float* __restrict__ s2,
                                                 int* __restrict__ cursor,
                                                 iv4* __restrict__ csr_pack, int E) {
  int e = blockIdx.x * 256 + threadIdx.x;
  if (e >= E) return;
  int src = edge_src[e];
  int dst = edge_dst[e];
  float sv = s2[dst];
  int pos = atomicAdd(&cursor[src], 1);
  iv4 pk; pk.x = e; pk.y = dst; pk.z = __float_as_int(sv); pk.w = 0;
  __builtin_nontemporal_store(pk, &csr_pack[pos]);
}

// ---------- K_edge: per-node wave; 2 edges/iter; depth-3 ring (6 in flight);
//            bf16 input gather; nt emb/csr; bf16 G ----------
__global__ __launch_bounds__(256) void k_edge(const unsigned short* __restrict__ inputB,
                                              const float* __restrict__ emb,
                                              const float* __restrict__ w3,
                                              const float* __restrict__ s1,
                                              const int* __restrict__ row_ptr,
                                              const iv4* __restrict__ csr_pack,
                                              unsigned short* __restrict__ Gb,
                                              float* __restrict__ rs, int N) {
  int lane = threadIdx.x & 63;
  int h = lane >> 5;     // which edge of the pair
  int c = lane & 31;     // feature sublane: features 4c..4c+3
  int n = blockIdx.x * 4 + (threadIdx.x >> 6);
  if (n >= N) return;
  int beg = row_ptr[n], end = row_ptr[n + 1];
  fv4 w3v = *(const fv4*)(w3 + 4 * c);
  float s1n = s1[n];
  fv4 gi = (fv4)(0.f), ge = (fv4)(0.f);
  float rsum = 0.f;

  fv4 z4 = (fv4)(0.f);
  ushort4 zy = make_ushort4(0, 0, 0, 0);
  fv4 x0 = z4, x1 = z4, x2 = z4;
  ushort4 y0 = zy, y1 = zy, y2 = zy;
  float sv0 = 0.f, sv1 = 0.f, sv2 = 0.f;
  bool va0 = false, va1 = false, va2 = false;
  iv4 pN; pN.x = 0; pN.y = 0; pN.z = 0; pN.w = 0;

  int i0 = beg + h;
  if (i0 < end) {
    iv4 p = __builtin_nontemporal_load(&csr_pack[i0]);
    sv0 = __int_as_float(p.z);
    x0 = __builtin_nontemporal_load((const fv4*)(emb + (size_t)p.x * RDIM + 4 * c));
    y0 = *(const ushort4*)(inputB + (size_t)p.y * F_IN + 4 * c);
    va0 = true;
  }
  if (i0 + 2 < end) {
    iv4 p = __builtin_nontemporal_load(&csr_pack[i0 + 2]);
    sv1 = __int_as_float(p.z);
    x1 = __builtin_nontemporal_load((const fv4*)(emb + (size_t)p.x * RDIM + 4 * c));
    y1 = *(const ushort4*)(inputB + (size_t)p.y * F_IN + 4 * c);
    va1 = true;
  }
  if (i0 + 4 < end) {
    iv4 p = __builtin_nontemporal_load(&csr_pack[i0 + 4]);
    sv2 = __int_as_float(p.z);
    x2 = __builtin_nontemporal_load((const fv4*)(emb + (size_t)p.x * RDIM + 4 * c));
    y2 = *(const ushort4*)(inputB + (size_t)p.y * F_IN + 4 * c);
    va2 = true;
  }
  if (i0 + 6 < end) pN = __builtin_nontemporal_load(&csr_pack[i0 + 6]);

  for (int i = beg; i < end; i += 2) {
    // refill slot3 data (edge i+6+h) from payload loaded last iteration
    fv4 xn = z4;
    ushort4 yn = zy;
    float svn = __int_as_float(pN.z);
    bool vn = (i + 6 + h) < end;
    if (vn) {
      xn = __builtin_nontemporal_load((const fv4*)(emb + (size_t)pN.x * RDIM + 4 * c));
      yn = *(const ushort4*)(inputB + (size_t)pN.y * F_IN + 4 * c);
    }
    // payload for edge i+8+h
    if (i + 8 + h < end) pN = __builtin_nontemporal_load(&csr_pack[i + 8 + h]);
    // compute on slot 0
    float q = x0.x * w3v.x + x0.y * w3v.y + x0.z * w3v.z + x0.w * w3v.w;
    #pragma unroll
    for (int m = 1; m < 32; m <<= 1) q += __shfl_xor(q, m, 64);  // within-half reduce
    float s = s1n + sv0 + q;
    float lr = s > 0.f ? s : ALPHA * s;
    float ee = va0 ? __expf(-lr) : 0.f;
    rsum += ee;
    gi.x += ee * bf2f(y0.x); gi.y += ee * bf2f(y0.y);
    gi.z += ee * bf2f(y0.z); gi.w += ee * bf2f(y0.w);
    ge.x += ee * x0.x; ge.y += ee * x0.y; ge.z += ee * x0.z; ge.w += ee * x0.w;
    // rotate ring (static renaming — stays in registers)
    x0 = x1; y0 = y1; sv0 = sv1; va0 = va1;
    x1 = x2; y1 = y2; sv1 = sv2; va1 = va2;
    x2 = xn; y2 = yn; sv2 = svn; va2 = vn;
  }

  rsum += __shfl_xor(rsum, 32, 64);
  gi.x += __shfl_xor(gi.x, 32, 64); gi.y += __shfl_xor(gi.y, 32, 64);
  gi.z += __shfl_xor(gi.z, 32, 64); gi.w += __shfl_xor(gi.w, 32, 64);
  ge.x += __shfl_xor(ge.x, 32, 64); ge.y += __shfl_xor(ge.y, 32, 64);
  ge.z += __shfl_xor(ge.z, 32, 64); ge.w += __shfl_xor(ge.w, 32, 64);

  float scale = rsum > 0.f ? 1.f / rsum : 0.f;
  if (h == 0) {
    unsigned short* Gn = Gb + (size_t)n * 256;
    ushort4 o;
    o.x = f2bf(gi.x * scale); o.y = f2bf(gi.y * scale);
    o.z = f2bf(gi.z * scale); o.w = f2bf(gi.w * scale);
    *(ushort4*)(Gn + 4 * c) = o;
    o.x = f2bf(ge.x * scale); o.y = f2bf(ge.y * scale);
    o.z = f2bf(ge.z * scale); o.w = f2bf(ge.w * scale);
    *(ushort4*)(Gn + 128 + 4 * c) = o;
  }
  if (lane == 0) rs[n] = rsum;
}

// ---------- K_out: MFMA bf16 GEMM: out = elu([inputB | Gb] @ aB^T), rs==0 -> 0 ----
__global__ __launch_bounds__(256) void k_out(const unsigned short* __restrict__ inputB,
                                             const unsigned short* __restrict__ Gb,
                                             const unsigned short* __restrict__ aB,
                                             const float* __restrict__ rs,
                                             float* __restrict__ out, int N) {
  int t = threadIdx.x;
  int w = t >> 6, lane = t & 63;
  int lg = lane >> 4, lr = lane & 15;
  int rowbase = blockIdx.x * 128 + w * 32;
  int koff = lg * 8;

  f4 acc[2][8];
  #pragma unroll
  for (int r = 0; r < 2; ++r)
    #pragma unroll
    for (int c = 0; c < 8; ++c) acc[r][c] = (f4)(0.f);

  #pragma unroll
  for (int ks = 0; ks < 12; ++ks) {
    const int k0 = ks * 32;
    bf8 Af[2], Bf[8];
    #pragma unroll
    for (int r = 0; r < 2; ++r) {
      int row = rowbase + r * 16 + lr;
      if (k0 < 128)
        Af[r] = *(const bf8*)(inputB + (size_t)row * 128 + k0 + koff);
      else
        Af[r] = *(const bf8*)(Gb + (size_t)row * 256 + (k0 - 128) + koff);
    }
    #pragma unroll
    for (int c = 0; c < 8; ++c)
      Bf[c] = *(const bf8*)(aB + (size_t)(c * 16 + lr) * KTOT + k0 + koff);
    #pragma unroll
    for (int r = 0; r < 2; ++r)
      #pragma unroll
      for (int c = 0; c < 8; ++c)
        acc[r][c] = __builtin_amdgcn_mfma_f32_16x16x32_bf16(Af[r], Bf[c], acc[r][c], 0, 0, 0);
  }

  #pragma unroll
  for (int r = 0; r < 2; ++r) {
    #pragma unroll
    for (int j = 0; j < 4; ++j) {
      int row = rowbase + r * 16 + lg * 4 + j;
      if (row >= N) continue;
      float rsv = rs[row];
      #pragma unroll
      for (int c = 0; c < 8; ++c) {
        float v = acc[r][c][j];
        float hh = v > 0.f ? v : (__expf(v) - 1.f);
        out[(size_t)row * 128 + c * 16 + lr] = (rsv == 0.f) ? 0.f : hh;
      }
    }
  }
}

extern "C" void kernel_launch(void* const* d_in, const int* in_sizes, int n_in,
                              void* d_out, int out_size, void* d_ws, size_t ws_size,
                              hipStream_t stream) {
  const float* input      = (const float*)d_in[0];
  const int*   edge       = (const int*)d_in[1];   // int32 [2,E] row-major
  const float* edge_embed = (const float*)d_in[2];
  const float* a          = (const float*)d_in[3];
  const float* a_2        = (const float*)d_in[4];
  float* out = (float*)d_out;
  int N = in_sizes[0] / F_IN;
  int E = in_sizes[1] / 2;
  const int* edge_src = edge;
  const int* edge_dst = edge + E;

  char* p = (char*)d_ws;
  auto take = [&](size_t bytes) { char* q = p; p += (bytes + 255) & ~(size_t)255; return q; };
  float* w        = (float*)take(KTOT * 4);        // w1|w2|w3 contiguous
  float* s1       = (float*)take((size_t)N * 4);
  float* s2       = (float*)take((size_t)N * 4);
  float* rs       = (float*)take((size_t)N * 4);
  int*   counts   = (int*)take((size_t)N * 4);
  int*   cursor   = (int*)take((size_t)N * 4);
  int*   row_ptr  = (int*)take((size_t)(N + 1) * 4);
  int*   bsums    = (int*)take(256 * 4);
  unsigned short* aB     = (unsigned short*)take((size_t)128 * KTOT * 2);
  unsigned short* inputB = (unsigned short*)take((size_t)N * 128 * 2);
  iv4*  csr_pack  = (iv4*)take((size_t)E * 16);
  unsigned short* Gb     = (unsigned short*)take((size_t)N * 256 * 2);
  (void)take(64 * 1024);   // tail pad: k_out overreads <=48 rows past N

  int zb = (N + 255) / 256;
  int SV = (N + 3) / 4;
  int HB = (E + 1023) / 1024;
  int NB = (N + 1023) / 1024;

  k_prep<<<192 + zb + 2, 256, 0, stream>>>(a, a_2, aB, counts, w, N, zb);
  k_sh<<<SV + HB, 256, 0, stream>>>(input, w, w + 128, s1, s2, inputB,
                                    edge_src, counts, N, E, SV);
  k_scanA<<<NB, 256, 0, stream>>>(counts, row_ptr, bsums, N);
  k_scanB<<<NB, 256, 0, stream>>>(row_ptr, cursor, bsums, N, NB);
  k_scatter<<<(E + 255) / 256, 256, 0, stream>>>(edge_src, edge_dst, s2, cursor,
                                                 csr_pack, E);
  k_edge<<<(N + 3) / 4, 256, 0, stream>>>(inputB, edge_embed, w + 256, s1,
                                          row_ptr, csr_pack, Gb, rs, N);
  k_out<<<(N + 127) / 128, 256, 0, stream>>>(inputB, Gb, aB, rs, out, N);
}